// Round 2
// baseline (245.999 us; speedup 1.0000x reference)
//
#include <hip/hip_runtime.h>

#define B_    128
#define T_    4096
#define V_    32
#define NHID  256
#define GW    0.25f
#define GDIM  (V_ * 2 * 32)     // 2048
#define FANIN (GDIM + 1)        // 2049

// ---------------------------------------------------------------------------
// Kernel 1: per-block = one (b, v-group-of-4). Ballot-compact valid t-indices
// (time is pre-sorted along T, mask-compaction preserves order) into u16 LDS
// lists, then 64 queries per variable do binary search + linear interp.
// ---------------------------------------------------------------------------
__global__ __launch_bounds__(256) void glimpse_kernel(
    const float* __restrict__ vals, const float* __restrict__ time_,
    const int* __restrict__ masks, const float* __restrict__ l_t,
    float* __restrict__ g_ws, float* __restrict__ mid_out)
{
    __shared__ float time_s[T_];                 // 16 KB
    __shared__ unsigned short idx_c[4][T_];      // 32 KB
    __shared__ int counts[4][4];                 // [wave][v]

    // XCD swizzle: put the 8 v-groups of each b (which share mask cache
    // lines) on the same XCD. grid = 1024, divisible by 8.
    int nwg   = gridDim.x;
    int bid   = blockIdx.x;
    int perx  = nwg >> 3;
    int wg    = (bid & 7) * perx + (bid >> 3);
    int b     = wg >> 3;
    int vg    = wg & 7;
    int v0    = vg * 4;

    int tid  = threadIdx.x;
    int lane = tid & 63;
    int wave = tid >> 6;
    unsigned long long lt_mask = (1ull << lane) - 1ull;

    const int*   mrow = masks + ((long)b * T_) * V_ + v0;
    const float* trow = time_ + (long)b * T_;

    int base0 = 0, base1 = 0, base2 = 0, base3 = 0;

    for (int c = 0; c < 16; ++c) {
        int t = c * 256 + tid;
        time_s[t] = trow[t];
        int4 m4 = *reinterpret_cast<const int4*>(mrow + (long)t * V_);
        unsigned long long bal0 = __ballot(m4.x != 0);
        unsigned long long bal1 = __ballot(m4.y != 0);
        unsigned long long bal2 = __ballot(m4.z != 0);
        unsigned long long bal3 = __ballot(m4.w != 0);
        if (lane == 0) {
            counts[wave][0] = __popcll(bal0);
            counts[wave][1] = __popcll(bal1);
            counts[wave][2] = __popcll(bal2);
            counts[wave][3] = __popcll(bal3);
        }
        __syncthreads();
        int pre0 = base0, pre1 = base1, pre2 = base2, pre3 = base3;
        #pragma unroll
        for (int w = 0; w < 4; ++w) {
            int c0 = counts[w][0], c1 = counts[w][1];
            int c2 = counts[w][2], c3 = counts[w][3];
            if (w < wave) { pre0 += c0; pre1 += c1; pre2 += c2; pre3 += c3; }
            base0 += c0; base1 += c1; base2 += c2; base3 += c3;
        }
        if (m4.x) idx_c[0][pre0 + (int)__popcll(bal0 & lt_mask)] = (unsigned short)t;
        if (m4.y) idx_c[1][pre1 + (int)__popcll(bal1 & lt_mask)] = (unsigned short)t;
        if (m4.z) idx_c[2][pre2 + (int)__popcll(bal2 & lt_mask)] = (unsigned short)t;
        if (m4.w) idx_c[3][pre3 + (int)__popcll(bal3 & lt_mask)] = (unsigned short)t;
        __syncthreads();   // protect counts[] rewrite next chunk
    }
    // base0..3 (uniform across threads) = nv for v0+0..3

    // ---- query phase: wave w handles variable v0+w, lane = query index j ----
    float lt = l_t[b];
    int v  = wave;
    int nv = (v == 0) ? base0 : (v == 1) ? base1 : (v == 2) ? base2 : base3;
    int j  = lane;                 // j = g*32 + k  (G-major)
    int gs = j >> 5, k = j & 31;
    float iscale = gs ? 5.0f : 1.0f;
    float half   = GW * iscale * 0.5f;
    float off    = -half + (float)k * (2.0f * half / 31.0f);

    float out = 0.0f;
    if (nv > 0) {
        float tmax = time_s[idx_c[v][nv - 1]];   // last valid = max (sorted)
        float q = (off + lt) * tmax;
        // lower_bound: first idx in [0,nv) with time >= q  (searchsorted 'left')
        int lo = 0, hi = nv;
        while (lo < hi) {
            int mid = (lo + hi) >> 1;
            float tm = time_s[idx_c[v][mid]];
            if (tm < q) lo = mid + 1; else hi = mid;
        }
        int left  = lo - 1; if (left < 0) left = 0; if (left > nv - 1) left = nv - 1;
        int right = lo;     if (right > nv - 1) right = nv - 1;
        int ti_l = idx_c[v][left];
        int ti_r = idx_c[v][right];
        float t_l = time_s[ti_l];
        float t_r = time_s[ti_r];
        float v_l = vals[((long)b * T_ + ti_l) * V_ + v0 + v];
        float v_r = vals[((long)b * T_ + ti_r) * V_ + v0 + v];
        float denom = t_r - t_l;
        float w = (denom > 0.0f) ? (q - t_l) / denom : 0.0f;
        out = v_l + w * (v_r - v_l);
    }
    int col = (v0 + v) * 64 + j;
    g_ws[(long)b * GDIM + col] = out;
    if (col == GDIM / 2) mid_out[b] = out;       // g[:, 1024]
}

// ---------------------------------------------------------------------------
// Kernel 2: grep = [g, l_t] @ W^T + bias.  Block per b; wave w computes
// h = w + 4*i (i = 0..63); lanes stride the 2049-wide row (coalesced) and
// shuffle-reduce.
// ---------------------------------------------------------------------------
__global__ __launch_bounds__(256) void grep_kernel(
    const float* __restrict__ g_ws, const float* __restrict__ l_t,
    const float* __restrict__ W, const float* __restrict__ bias,
    float* __restrict__ out)
{
    __shared__ float gsh[GDIM + 1];
    int b = blockIdx.x, tid = threadIdx.x;
    int lane = tid & 63, wave = tid >> 6;
    for (int jj = tid; jj < GDIM; jj += 256) gsh[jj] = g_ws[(long)b * GDIM + jj];
    if (tid == 0) gsh[GDIM] = l_t[b];
    __syncthreads();

    for (int i = 0; i < NHID / 4; ++i) {
        int h = wave + 4 * i;
        const float* wr = W + (long)h * FANIN;
        float acc = 0.0f;
        #pragma unroll
        for (int c = 0; c < 32; ++c) {           // 32*64 = 2048
            int jj = c * 64 + lane;
            acc += wr[jj] * gsh[jj];
        }
        if (lane == 0) acc += wr[GDIM] * gsh[GDIM];   // l_t term
        #pragma unroll
        for (int s = 32; s > 0; s >>= 1) acc += __shfl_down(acc, s, 64);
        if (lane == 0) out[(long)b * NHID + h] = acc + bias[h];
    }
}

extern "C" void kernel_launch(void* const* d_in, const int* in_sizes, int n_in,
                              void* d_out, int out_size, void* d_ws, size_t ws_size,
                              hipStream_t stream)
{
    const float* vals  = (const float*)d_in[0];
    const float* time_ = (const float*)d_in[1];
    const int*   masks = (const int*)d_in[2];
    // d_in[3] = lengths (unused by the reference outputs)
    const float* l_t   = (const float*)d_in[4];
    const float* W     = (const float*)d_in[5];
    const float* bias  = (const float*)d_in[6];

    float* out  = (float*)d_out;              // [B*NHID] grep, then [B] mid
    float* g_ws = (float*)d_ws;               // [B, GDIM] f32 = 1 MB scratch

    glimpse_kernel<<<B_ * 8, 256, 0, stream>>>(vals, time_, masks, l_t,
                                               g_ws, out + (long)B_ * NHID);
    grep_kernel<<<B_, 256, 0, stream>>>(g_ws, l_t, W, bias, out);
}

// Round 3
// 181.945 us; speedup vs baseline: 1.3521x; 1.3521x over previous
//
#include <hip/hip_runtime.h>

typedef unsigned long long ull;

#define B_    128
#define T_    4096
#define V_    32
#define NHID  256
#define GDIM  2048            // V * 2 * 32
#define GW    0.25f

// ---------------------------------------------------------------------------
// Kernel 1: block = (b, half). 16 variables per block, 512 threads (8 waves).
// Thread (tl = tid>>2, vq = tid&3) loads int4 of vars vq*4..vq*4+3 at t.
// Pass 1 (no barriers): stream masks, ballots -> per-(chunk,wave,var) counts.
// Prefix stages -> wavepre table. Pass 2: register re-ballot -> compacted
// u16 time-index lists per var. Query: 1024 interpolations via binary search.
// ---------------------------------------------------------------------------
__global__ __launch_bounds__(512) void glimpse_kernel(
    const float* __restrict__ vals, const float* __restrict__ time_,
    const int* __restrict__ masks, const float* __restrict__ l_t,
    float* __restrict__ g_ws, float* __restrict__ mid_out)
{
    __shared__ float time_s[T_];                    // 16 KB
    __shared__ unsigned short idx_c[16][T_];        // 128 KB
    __shared__ unsigned char  cnt8[32][8][16];      // 4 KB   [chunk][wave][var]
    __shared__ unsigned short pref[32][16];         // 1 KB   chunk-exclusive prefix
    __shared__ unsigned short wavepre[32][8][16];   // 8 KB
    __shared__ int nv_s[16];

    int bid = blockIdx.x;
    int w2  = (bid & 7) * 32 + (bid >> 3);   // co-locate sibling halves per XCD
    int b    = w2 >> 1;
    int half = w2 & 1;

    int tid = threadIdx.x, lane = tid & 63, wave = tid >> 6;
    int vq = tid & 3, tl = tid >> 2;         // tl in [0,128)

    const float* trow = time_ + (long)b * T_;
    for (int i = tid; i < T_; i += 512) time_s[i] = trow[i];

    const int* mbase = masks + ((long)b * T_) * V_ + half * 16 + vq * 4;
    ull qm  = 0x1111111111111111ull << vq;   // lanes with lane%4 == vq
    ull ltm = (1ull << lane) - 1ull;

    unsigned f0 = 0, f1 = 0, f2 = 0, f3 = 0;

    #pragma unroll 4
    for (int c = 0; c < 32; ++c) {
        int t = c * 128 + tl;
        int4 m4 = *reinterpret_cast<const int4*>(mbase + (long)t * V_);
        ull bl0 = __ballot(m4.x != 0);
        ull bl1 = __ballot(m4.y != 0);
        ull bl2 = __ballot(m4.z != 0);
        ull bl3 = __ballot(m4.w != 0);
        f0 |= (unsigned)(m4.x != 0) << c;
        f1 |= (unsigned)(m4.y != 0) << c;
        f2 |= (unsigned)(m4.z != 0) << c;
        f3 |= (unsigned)(m4.w != 0) << c;
        if (lane < 16) {
            // lane L writes var v=L (= (L>>2)*4 + (L&3)): component L&3, quad L>>2
            int li = lane & 3;
            ull bs = (li == 0) ? bl0 : (li == 1) ? bl1 : (li == 2) ? bl2 : bl3;
            ull qq = 0x1111111111111111ull << (lane >> 2);
            cnt8[c][wave][lane] = (unsigned char)__popcll(bs & qq);
        }
    }
    __syncthreads();

    {   // A: per-chunk totals (512 threads = 32 chunks x 16 vars)
        int c = tid >> 4, v = tid & 15;
        int s = 0;
        #pragma unroll
        for (int w = 0; w < 8; ++w) s += cnt8[c][w][v];
        pref[c][v] = (unsigned short)s;
    }
    __syncthreads();
    if (tid < 16) {   // B: exclusive scan over chunks (16 lanes, 32 iters)
        int run = 0;
        for (int c = 0; c < 32; ++c) {
            int x = pref[c][tid];
            pref[c][tid] = (unsigned short)run;
            run += x;
        }
        nv_s[tid] = run;
    }
    __syncthreads();
    {   // C: wave-level exclusive prefix within chunk
        int c = tid >> 4, v = tid & 15;
        int run = pref[c][v];
        #pragma unroll
        for (int w = 0; w < 8; ++w) {
            wavepre[c][w][v] = (unsigned short)run;
            run += cnt8[c][w][v];
        }
    }
    __syncthreads();

    // Pass 2: re-ballot from register flags, write compacted index lists.
    int vb = vq * 4;
    #pragma unroll 4
    for (int c = 0; c < 32; ++c) {
        unsigned short t = (unsigned short)(c * 128 + tl);
        ull bl0 = __ballot((f0 >> c) & 1);
        ull bl1 = __ballot((f1 >> c) & 1);
        ull bl2 = __ballot((f2 >> c) & 1);
        ull bl3 = __ballot((f3 >> c) & 1);
        if ((f0 >> c) & 1) idx_c[vb+0][wavepre[c][wave][vb+0] + __popcll(bl0 & qm & ltm)] = t;
        if ((f1 >> c) & 1) idx_c[vb+1][wavepre[c][wave][vb+1] + __popcll(bl1 & qm & ltm)] = t;
        if ((f2 >> c) & 1) idx_c[vb+2][wavepre[c][wave][vb+2] + __popcll(bl2 & qm & ltm)] = t;
        if ((f3 >> c) & 1) idx_c[vb+3][wavepre[c][wave][vb+3] + __popcll(bl3 & qm & ltm)] = t;
    }
    __syncthreads();

    // Query phase: 512 threads x 2 queries = 16 vars x 64 queries.
    int v  = tid >> 5;       // 0..15
    int k  = tid & 31;       // glimpse index within scale
    int nv = nv_s[v];
    float ltv = l_t[b];
    int vg = half * 16 + v;
    float tmax = 0.0f;
    if (nv > 0) tmax = time_s[idx_c[v][nv - 1]];

    #pragma unroll
    for (int g = 0; g < 2; ++g) {
        int j = g * 32 + k;
        float hw  = GW * (g ? 5.0f : 1.0f) * 0.5f;
        float off = -hw + (float)k * (2.0f * hw / 31.0f);
        float outv = 0.0f;
        if (nv > 0) {
            float q = (off + ltv) * tmax;
            int lo = 0, hi = nv;
            while (lo < hi) {
                int mid = (lo + hi) >> 1;
                float tm = time_s[idx_c[v][mid]];
                if (tm < q) lo = mid + 1; else hi = mid;
            }
            int left  = lo - 1; if (left < 0) left = 0; if (left > nv - 1) left = nv - 1;
            int right = lo;     if (right > nv - 1) right = nv - 1;
            int til = idx_c[v][left], tir = idx_c[v][right];
            float tle = time_s[til], tre = time_s[tir];
            float vle = vals[((long)b * T_ + til) * V_ + vg];
            float vre = vals[((long)b * T_ + tir) * V_ + vg];
            float den = tre - tle;
            float wt  = (den > 0.0f) ? (q - tle) / den : 0.0f;
            outv = vle + wt * (vre - vle);
        }
        int col = vg * 64 + j;
        g_ws[(long)b * GDIM + col] = outv;
        if (col == 1024) mid_out[b] = outv;    // g[:, 1024]
    }
}

// ---------------------------------------------------------------------------
// Kernel 2: grep = [g, l_t] @ W^T + bias.
// 256 blocks (8 b-groups x 32 h-groups), 4 waves. Wave holds 4 b-rows of g
// in 128 registers; per h: coalesced W row, 4 FMAs per element, butterfly
// reduce, lane0 writes 4 outputs.
// ---------------------------------------------------------------------------
__global__ __launch_bounds__(256) void grep_kernel(
    const float* __restrict__ g_ws, const float* __restrict__ l_t,
    const float* __restrict__ W, const float* __restrict__ bias,
    float* __restrict__ out)
{
    int bid = blockIdx.x;
    int w2 = (bid & 7) * 32 + (bid >> 3);    // co-locate same-W blocks per XCD
    int ht = w2 >> 3;                        // 32 groups of 8 h
    int bg = w2 & 7;                         // 8 groups of 16 b
    int tid = threadIdx.x, lane = tid & 63, wave = tid >> 6;
    int b0 = bg * 16 + wave * 4;
    int h0 = ht * 8;

    float ga[4][32];
    #pragma unroll
    for (int i = 0; i < 4; ++i) {
        #pragma unroll
        for (int c = 0; c < 32; ++c)
            ga[i][c] = g_ws[(long)(b0 + i) * GDIM + c * 64 + lane];
    }
    float lt0 = l_t[b0], lt1 = l_t[b0+1], lt2 = l_t[b0+2], lt3 = l_t[b0+3];

    for (int hh = 0; hh < 8; ++hh) {
        int h = h0 + hh;
        const float* wr = W + (long)h * (GDIM + 1);
        float a0 = 0.f, a1 = 0.f, a2 = 0.f, a3 = 0.f;
        #pragma unroll
        for (int c = 0; c < 32; ++c) {
            float wv = wr[c * 64 + lane];
            a0 += wv * ga[0][c];
            a1 += wv * ga[1][c];
            a2 += wv * ga[2][c];
            a3 += wv * ga[3][c];
        }
        if (lane == 0) {
            float wl = wr[GDIM];
            a0 += wl * lt0; a1 += wl * lt1; a2 += wl * lt2; a3 += wl * lt3;
        }
        #pragma unroll
        for (int s = 32; s; s >>= 1) {
            a0 += __shfl_xor(a0, s, 64);
            a1 += __shfl_xor(a1, s, 64);
            a2 += __shfl_xor(a2, s, 64);
            a3 += __shfl_xor(a3, s, 64);
        }
        if (lane == 0) {
            float bv = bias[h];
            out[(long)(b0 + 0) * NHID + h] = a0 + bv;
            out[(long)(b0 + 1) * NHID + h] = a1 + bv;
            out[(long)(b0 + 2) * NHID + h] = a2 + bv;
            out[(long)(b0 + 3) * NHID + h] = a3 + bv;
        }
    }
}

extern "C" void kernel_launch(void* const* d_in, const int* in_sizes, int n_in,
                              void* d_out, int out_size, void* d_ws, size_t ws_size,
                              hipStream_t stream)
{
    const float* vals  = (const float*)d_in[0];
    const float* time_ = (const float*)d_in[1];
    const int*   masks = (const int*)d_in[2];
    // d_in[3] = lengths (unused by the reference outputs)
    const float* l_t   = (const float*)d_in[4];
    const float* W     = (const float*)d_in[5];
    const float* bias  = (const float*)d_in[6];

    float* out  = (float*)d_out;              // [B*NHID] grep, then [B] mid
    float* g_ws = (float*)d_ws;               // [B, GDIM] f32 = 1 MB scratch

    glimpse_kernel<<<B_ * 2, 512, 0, stream>>>(vals, time_, masks, l_t,
                                               g_ws, out + (long)B_ * NHID);
    grep_kernel<<<256, 256, 0, stream>>>(g_ws, l_t, W, bias, out);
}

// Round 4
// 175.528 us; speedup vs baseline: 1.4015x; 1.0366x over previous
//
#include <hip/hip_runtime.h>

typedef unsigned long long ull;

#define B_    128
#define T_    4096
#define V_    32
#define NHID  256
#define GDIM  2048            // V * 2 * 32
#define GW    0.25f
#define CAP   3584            // idx capacity/var; input nv~2048+-65, clamped writes

// ---------------------------------------------------------------------------
// Kernel 1: block = (b, v-quarter-of-8). 512 threads (8 waves), 2 blocks/CU.
// Thread (tl = tid>>1, vq = tid&1) loads int4 of vars v0+vq*4.. at t.
// Pass 1: stream masks, ballots -> per-(chunk,wave,var) counts (regs keep
// valid flags). Prefix stages -> wavepre. Pass 2: register re-ballot ->
// compacted u16 time-index lists. Query: wave = var, lane = query j.
// ---------------------------------------------------------------------------
__global__ __launch_bounds__(512, 4) void glimpse_kernel(
    const float* __restrict__ vals, const float* __restrict__ time_,
    const int* __restrict__ masks, const float* __restrict__ l_t,
    float* __restrict__ g_ws, float* __restrict__ mid_out)
{
    __shared__ float time_s[T_];                  // 16 KB
    __shared__ unsigned short idx_c[8][CAP];      // 56 KB
    __shared__ unsigned char  cnt8[16][8][8];     // 1 KB  [chunk][wave][var]
    __shared__ unsigned short pref[16][8];        // 256 B (chunk-exclusive)
    __shared__ unsigned short wavepre[16][8][8];  // 2 KB
    __shared__ int nv_s[8];

    // XCD swizzle: each XCD owns 16 consecutive b x all 4 v-quarters so the
    // sibling blocks sharing each 128B mask/vals line share one L2.
    int bid = blockIdx.x;
    int wg  = (bid & 7) * 64 + (bid >> 3);
    int b   = wg >> 2;
    int v0  = (wg & 3) * 8;

    int tid = threadIdx.x, lane = tid & 63, wave = tid >> 6;
    int vq = tid & 1, tl = tid >> 1;              // tl in [0,256)

    {   // stage time row (float4, 2 iters)
        const float4* trow4 = (const float4*)(time_ + (long)b * T_);
        float4* ts4 = (float4*)time_s;
        for (int i = tid; i < T_ / 4; i += 512) ts4[i] = trow4[i];
    }

    const int* mbase = masks + ((long)b * T_) * V_ + v0 + vq * 4;
    ull qm  = vq ? 0xAAAAAAAAAAAAAAAAull : 0x5555555555555555ull;
    ull ltm = (1ull << lane) - 1ull;

    unsigned f0 = 0, f1 = 0, f2 = 0, f3 = 0;

    #pragma unroll 4
    for (int c = 0; c < 16; ++c) {
        int t = c * 256 + tl;
        int4 m4 = *reinterpret_cast<const int4*>(mbase + (long)t * V_);
        ull bl0 = __ballot(m4.x != 0);
        ull bl1 = __ballot(m4.y != 0);
        ull bl2 = __ballot(m4.z != 0);
        ull bl3 = __ballot(m4.w != 0);
        f0 |= (unsigned)(m4.x != 0) << c;
        f1 |= (unsigned)(m4.y != 0) << c;
        f2 |= (unsigned)(m4.z != 0) << c;
        f3 |= (unsigned)(m4.w != 0) << c;
        if (lane < 8) {
            // lane L counts var L = (L>>2)*4 + (L&3): quad L>>2, component L&3
            int li = lane & 3;
            ull bs = (li == 0) ? bl0 : (li == 1) ? bl1 : (li == 2) ? bl2 : bl3;
            ull qq = (lane >> 2) ? 0xAAAAAAAAAAAAAAAAull : 0x5555555555555555ull;
            cnt8[c][wave][lane] = (unsigned char)__popcll(bs & qq);
        }
    }
    __syncthreads();

    if (tid < 128) {   // A: per-chunk totals (16 chunks x 8 vars)
        int c = tid >> 3, v = tid & 7;
        int s = 0;
        #pragma unroll
        for (int w = 0; w < 8; ++w) s += cnt8[c][w][v];
        pref[c][v] = (unsigned short)s;
    }
    __syncthreads();
    if (tid < 8) {     // B: exclusive scan over chunks
        int run = 0;
        for (int c = 0; c < 16; ++c) {
            int x = pref[c][tid];
            pref[c][tid] = (unsigned short)run;
            run += x;
        }
        nv_s[tid] = (run < CAP) ? run : CAP;
    }
    __syncthreads();
    if (tid < 128) {   // C: wave-level exclusive prefix within chunk
        int c = tid >> 3, v = tid & 7;
        int run = pref[c][v];
        #pragma unroll
        for (int w = 0; w < 8; ++w) {
            wavepre[c][w][v] = (unsigned short)run;
            run += cnt8[c][w][v];
        }
    }
    __syncthreads();

    // Pass 2: re-ballot from register flags, write compacted index lists.
    int vb = vq * 4;
    #pragma unroll 4
    for (int c = 0; c < 16; ++c) {
        unsigned short t = (unsigned short)(c * 256 + tl);
        ull bl0 = __ballot((f0 >> c) & 1);
        ull bl1 = __ballot((f1 >> c) & 1);
        ull bl2 = __ballot((f2 >> c) & 1);
        ull bl3 = __ballot((f3 >> c) & 1);
        if ((f0 >> c) & 1) { int r = wavepre[c][wave][vb+0] + (int)__popcll(bl0 & qm & ltm); if (r < CAP) idx_c[vb+0][r] = t; }
        if ((f1 >> c) & 1) { int r = wavepre[c][wave][vb+1] + (int)__popcll(bl1 & qm & ltm); if (r < CAP) idx_c[vb+1][r] = t; }
        if ((f2 >> c) & 1) { int r = wavepre[c][wave][vb+2] + (int)__popcll(bl2 & qm & ltm); if (r < CAP) idx_c[vb+2][r] = t; }
        if ((f3 >> c) & 1) { int r = wavepre[c][wave][vb+3] + (int)__popcll(bl3 & qm & ltm); if (r < CAP) idx_c[vb+3][r] = t; }
    }
    __syncthreads();

    // Query phase: wave = var (0..7), lane = query j (G-major: j = g*32+k).
    int v  = wave;
    int j  = lane;
    int gs = j >> 5, k = j & 31;
    int nv = nv_s[v];
    float ltv = l_t[b];
    int vg = v0 + v;

    float outv = 0.0f;
    if (nv > 0) {
        float tmax = time_s[idx_c[v][nv - 1]];    // last valid = max (sorted)
        float hw  = GW * (gs ? 5.0f : 1.0f) * 0.5f;
        float off = -hw + (float)k * (2.0f * hw / 31.0f);
        float qv  = (off + ltv) * tmax;
        // lower_bound: first idx in [0,nv) with time >= qv (searchsorted left)
        int lo = 0, hi = nv;
        while (lo < hi) {
            int mid = (lo + hi) >> 1;
            float tm = time_s[idx_c[v][mid]];
            if (tm < qv) lo = mid + 1; else hi = mid;
        }
        int left  = lo - 1; if (left < 0) left = 0; if (left > nv - 1) left = nv - 1;
        int right = lo;     if (right > nv - 1) right = nv - 1;
        int til = idx_c[v][left], tir = idx_c[v][right];
        float tle = time_s[til], tre = time_s[tir];
        float vle = vals[((long)b * T_ + til) * V_ + vg];
        float vre = vals[((long)b * T_ + tir) * V_ + vg];
        float den = tre - tle;
        float wt  = (den > 0.0f) ? (qv - tle) / den : 0.0f;
        outv = vle + wt * (vre - vle);
    }
    int col = vg * 64 + j;
    g_ws[(long)b * GDIM + col] = outv;
    if (col == 1024) mid_out[b] = outv;           // g[:, 1024]
}

// ---------------------------------------------------------------------------
// Kernel 2: grep = [g, l_t] @ W^T + bias.
// 256 blocks (8 b-groups x 32 h-groups), 4 waves. Wave holds 4 b-rows of g
// in 128 registers; per h: coalesced W row, 4 FMAs per element, butterfly
// reduce, lane0 writes 4 outputs.
// ---------------------------------------------------------------------------
__global__ __launch_bounds__(256) void grep_kernel(
    const float* __restrict__ g_ws, const float* __restrict__ l_t,
    const float* __restrict__ W, const float* __restrict__ bias,
    float* __restrict__ out)
{
    int bid = blockIdx.x;
    int w2 = (bid & 7) * 32 + (bid >> 3);    // co-locate same-W blocks per XCD
    int ht = w2 >> 3;                        // 32 groups of 8 h
    int bg = w2 & 7;                         // 8 groups of 16 b
    int tid = threadIdx.x, lane = tid & 63, wave = tid >> 6;
    int b0 = bg * 16 + wave * 4;
    int h0 = ht * 8;

    float ga[4][32];
    #pragma unroll
    for (int i = 0; i < 4; ++i) {
        #pragma unroll
        for (int c = 0; c < 32; ++c)
            ga[i][c] = g_ws[(long)(b0 + i) * GDIM + c * 64 + lane];
    }
    float lt0 = l_t[b0], lt1 = l_t[b0+1], lt2 = l_t[b0+2], lt3 = l_t[b0+3];

    for (int hh = 0; hh < 8; ++hh) {
        int h = h0 + hh;
        const float* wr = W + (long)h * (GDIM + 1);
        float a0 = 0.f, a1 = 0.f, a2 = 0.f, a3 = 0.f;
        #pragma unroll
        for (int c = 0; c < 32; ++c) {
            float wv = wr[c * 64 + lane];
            a0 += wv * ga[0][c];
            a1 += wv * ga[1][c];
            a2 += wv * ga[2][c];
            a3 += wv * ga[3][c];
        }
        if (lane == 0) {
            float wl = wr[GDIM];
            a0 += wl * lt0; a1 += wl * lt1; a2 += wl * lt2; a3 += wl * lt3;
        }
        #pragma unroll
        for (int s = 32; s; s >>= 1) {
            a0 += __shfl_xor(a0, s, 64);
            a1 += __shfl_xor(a1, s, 64);
            a2 += __shfl_xor(a2, s, 64);
            a3 += __shfl_xor(a3, s, 64);
        }
        if (lane == 0) {
            float bv = bias[h];
            out[(long)(b0 + 0) * NHID + h] = a0 + bv;
            out[(long)(b0 + 1) * NHID + h] = a1 + bv;
            out[(long)(b0 + 2) * NHID + h] = a2 + bv;
            out[(long)(b0 + 3) * NHID + h] = a3 + bv;
        }
    }
}

extern "C" void kernel_launch(void* const* d_in, const int* in_sizes, int n_in,
                              void* d_out, int out_size, void* d_ws, size_t ws_size,
                              hipStream_t stream)
{
    const float* vals  = (const float*)d_in[0];
    const float* time_ = (const float*)d_in[1];
    const int*   masks = (const int*)d_in[2];
    // d_in[3] = lengths (unused by the reference outputs)
    const float* l_t   = (const float*)d_in[4];
    const float* W     = (const float*)d_in[5];
    const float* bias  = (const float*)d_in[6];

    float* out  = (float*)d_out;              // [B*NHID] grep, then [B] mid
    float* g_ws = (float*)d_ws;               // [B, GDIM] f32 = 1 MB scratch

    glimpse_kernel<<<B_ * 4, 512, 0, stream>>>(vals, time_, masks, l_t,
                                               g_ws, out + (long)B_ * NHID);
    grep_kernel<<<256, 256, 0, stream>>>(g_ws, l_t, W, bias, out);
}

// Round 5
// 164.955 us; speedup vs baseline: 1.4913x; 1.0641x over previous
//
#include <hip/hip_runtime.h>

typedef unsigned long long ull;

#define B_    128
#define T_    4096
#define V_    32
#define NHID  256
#define GDIM  2048            // V * 2 * 32
#define GW    0.25f

// ---------------------------------------------------------------------------
// K1: masks -> raw ballot bitmask words in global scratch.
// Block = (b, v-quarter(8 vars), T-quarter(1024 t)), 256 threads, no LDS.
// Thread (tl=tid>>1, vq=tid&1) loads int4 of vars vq4*8+vq*4.. at t.
// Ballot word for component x: even bits = var vq4*8+x (t=base+i at lane 2i),
// odd bits = var vq4*8+4+x. Stored raw; K2 rank/select uses a parity mask.
// gm[((b*4+vq4)*4 + comp)*128 + word], word = t/32.
// ---------------------------------------------------------------------------
__global__ __launch_bounds__(256) void mask_kernel(
    const int* __restrict__ masks, ull* __restrict__ gm)
{
    int bid = blockIdx.x;
    int wg  = (bid & 7) * 256 + (bid >> 3);   // XCD swizzle: siblings adjacent
    int vq4 = wg & 3;
    int tq  = (wg >> 2) & 3;
    int b   = wg >> 4;

    int tid = threadIdx.x, lane = tid & 63, wave = tid >> 6;
    int vq = tid & 1, tl = tid >> 1;          // tl in [0,128)

    const int* mbase = masks + ((long)b * T_) * V_ + vq4 * 8 + vq * 4;
    int wbase = (b * 4 + vq4) * 4 * 128 + tq * 32 + wave;

    int4 m[8];
    #pragma unroll
    for (int c = 0; c < 8; ++c)
        m[c] = *reinterpret_cast<const int4*>(mbase + (long)(tq*1024 + c*128 + tl) * V_);

    #pragma unroll
    for (int c = 0; c < 8; ++c) {
        ull bl0 = __ballot(m[c].x != 0);
        ull bl1 = __ballot(m[c].y != 0);
        ull bl2 = __ballot(m[c].z != 0);
        ull bl3 = __ballot(m[c].w != 0);
        if (lane < 4) {
            ull w = (lane == 0) ? bl0 : (lane == 1) ? bl1 : (lane == 2) ? bl2 : bl3;
            gm[wbase + lane * 128 + c * 4] = w;
        }
    }
}

// ---------------------------------------------------------------------------
// K2: per-block = (b, 4 vars of one parity). 256 threads (4 waves).
// Stage time row + 4 comps' bitmask words; wave w builds rank prefix for its
// var via popcount + shfl scan; then 1 query/thread: bsearch full time row,
// rank at p, word-select right endpoint, clz for left, interp.
// ---------------------------------------------------------------------------
__global__ __launch_bounds__(256) void query_kernel(
    const float* __restrict__ vals, const float* __restrict__ time_,
    const ull* __restrict__ gm, const float* __restrict__ l_t,
    float* __restrict__ g_ws, float* __restrict__ mid_out)
{
    __shared__ float time_s[T_];              // 16 KB
    __shared__ ull   mask64[4][128];          // 4 KB
    __shared__ unsigned short rank16[4][128]; // 1 KB
    __shared__ int   nv_s[4];
    __shared__ float tmax_s[4];

    int bid = blockIdx.x;
    int wg  = (bid & 7) * 128 + (bid >> 3);   // co-locate all vgs of b per XCD
    int b   = wg >> 3;
    int vg  = wg & 7;
    int vq4 = vg >> 1, par = vg & 1;

    int tid = threadIdx.x, lane = tid & 63, wave = tid >> 6;

    {   // stage time (float4) and mask words
        const float4* t4 = (const float4*)(time_ + (long)b * T_);
        float4* s4 = (float4*)time_s;
        #pragma unroll
        for (int i = 0; i < 4; ++i) s4[tid + i * 256] = t4[tid + i * 256];
        const ull* src = gm + (long)(b * 4 + vq4) * 4 * 128;
        ((ull*)mask64)[tid]       = src[tid];
        ((ull*)mask64)[tid + 256] = src[tid + 256];
    }
    __syncthreads();

    ull pm = 0x5555555555555555ull << par;

    {   // rank scan: wave w handles its own var (comp w)
        ull w0 = mask64[wave][2*lane]     & pm;
        ull w1 = mask64[wave][2*lane + 1] & pm;
        int pa = __popcll(w0), pb = __popcll(w1);
        int x = pa + pb, inc = x;
        #pragma unroll
        for (int off = 1; off < 64; off <<= 1) {
            int y = __shfl_up(inc, off, 64);
            if (lane >= off) inc += y;
        }
        int excl = inc - x;
        rank16[wave][2*lane]     = (unsigned short)excl;
        rank16[wave][2*lane + 1] = (unsigned short)(excl + pa);
        if (lane == 63) nv_s[wave] = inc;
        ull nzball = __ballot((w0 | w1) != 0ull);
        if (nzball) {
            int hl = 63 - __clzll(nzball);
            if (lane == hl) {
                ull wsel = w1 ? w1 : w0;
                int widx = 2*lane + (w1 ? 1 : 0);
                int bp = 63 - __clzll(wsel);
                tmax_s[wave] = time_s[widx * 32 + (bp >> 1)];
            }
        }
    }
    __syncthreads();

    // ---- query: wave = var, lane = query j (G-major j = g*32+k) ----
    int v   = wave;
    int vgl = vq4 * 8 + par * 4 + v;
    int j   = lane, gs = j >> 5, k = j & 31;
    int nv  = nv_s[v];
    float outv = 0.0f;
    if (nv > 0) {
        float hw  = GW * (gs ? 5.0f : 1.0f) * 0.5f;
        float off = -hw + (float)k * (2.0f * hw / 31.0f);
        float qv  = (off + l_t[b]) * tmax_s[v];

        int lo = 0, hi = T_;                  // searchsorted 'left' on full row
        while (lo < hi) { int mid = (lo + hi) >> 1;
                          if (time_s[mid] < qv) lo = mid + 1; else hi = mid; }
        int p = lo;

        int r;                                 // rank = # valid with time < qv
        if (p >= T_) r = nv;
        else {
            int wr = p >> 5, tin = p & 31;
            ull below = tin ? ((1ull << (2 * tin)) - 1ull) : 0ull;
            r = (int)rank16[v][wr] + __popcll(mask64[v][wr] & pm & below);
        }
        int rc = (r > nv - 1) ? nv - 1 : r;
        int lc = r - 1; if (lc < 0) lc = 0; if (lc > nv - 1) lc = nv - 1;

        // select rc-th valid: bsearch rank table, then in-word descent
        int ws = 0;
        #pragma unroll
        for (int s = 64; s; s >>= 1) {
            int t2 = ws + s;
            if (t2 < 128 && (int)rank16[v][t2] <= rc) ws = t2;
        }
        int jj = rc - (int)rank16[v][ws];
        ull ww = mask64[v][ws] & pm;
        int bitpos = 0;
        #pragma unroll
        for (int half = 32; half; half >>= 1) {
            ull lm = (half == 32) ? 0xFFFFFFFFull : ((1ull << half) - 1ull);
            int c = __popcll(ww & lm);
            if (jj >= c) { jj -= c; ww >>= half; bitpos += half; }
        }
        int sel_r = ws * 32 + (bitpos >> 1);

        int sel_l = sel_r;
        if (lc != rc) {                        // previous set bit
            ull wb = mask64[v][ws] & pm & (bitpos ? ((1ull << bitpos) - 1ull) : 0ull);
            int wsx = ws;
            while (!wb) { --wsx; wb = mask64[v][wsx] & pm; }
            int bp = 63 - __clzll(wb);
            sel_l = wsx * 32 + (bp >> 1);
        }

        float tle = time_s[sel_l], tre = time_s[sel_r];
        float vle = vals[((long)b * T_ + sel_l) * V_ + vgl];
        float vre = vals[((long)b * T_ + sel_r) * V_ + vgl];
        float den = tre - tle;
        float wt  = (den > 0.0f) ? (qv - tle) / den : 0.0f;
        outv = vle + wt * (vre - vle);
    }
    int col = vgl * 64 + j;
    g_ws[(long)b * GDIM + col] = outv;
    if (col == 1024) mid_out[b] = outv;       // g[:, 1024]
}

// ---------------------------------------------------------------------------
// K3: grep = [g, l_t] @ W^T + bias. 1024 blocks (16 bg x 64 hg), 4 waves.
// Wave holds 2 b-rows of g as float4 regs; W rows read coalesced (dword;
// compiler merges), shared across the 16 bg siblings on one XCD.
// ---------------------------------------------------------------------------
__global__ __launch_bounds__(256) void grep_kernel(
    const float* __restrict__ g_ws, const float* __restrict__ l_t,
    const float* __restrict__ W, const float* __restrict__ bias,
    float* __restrict__ out)
{
    int bid = blockIdx.x;
    int wg = (bid & 7) * 128 + (bid >> 3);
    int hg = wg >> 4;                        // 64 groups of 4 h
    int bg = wg & 15;                        // 16 groups of 8 b
    int tid = threadIdx.x, lane = tid & 63, wave = tid >> 6;
    int b0 = bg * 8 + wave * 2;
    int h0 = hg * 4;

    float4 ga[2][8];
    #pragma unroll
    for (int i = 0; i < 2; ++i)
        #pragma unroll
        for (int c = 0; c < 8; ++c)
            ga[i][c] = *(const float4*)(g_ws + (long)(b0 + i) * GDIM + c * 256 + lane * 4);
    float lt0 = l_t[b0], lt1 = l_t[b0 + 1];

    #pragma unroll
    for (int hh = 0; hh < 4; ++hh) {
        int h = h0 + hh;
        const float* wr = W + (long)h * (GDIM + 1);
        float a0 = 0.f, a1 = 0.f;
        #pragma unroll
        for (int c = 0; c < 8; ++c) {
            const float* wp = wr + c * 256 + lane * 4;
            float w0 = wp[0], w1 = wp[1], w2 = wp[2], w3 = wp[3];
            a0 += w0*ga[0][c].x + w1*ga[0][c].y + w2*ga[0][c].z + w3*ga[0][c].w;
            a1 += w0*ga[1][c].x + w1*ga[1][c].y + w2*ga[1][c].z + w3*ga[1][c].w;
        }
        if (lane == 0) { float wl = wr[GDIM]; a0 += wl * lt0; a1 += wl * lt1; }
        #pragma unroll
        for (int s = 32; s; s >>= 1) {
            a0 += __shfl_xor(a0, s, 64);
            a1 += __shfl_xor(a1, s, 64);
        }
        if (lane == 0) {
            float bv = bias[h];
            out[(long)(b0 + 0) * NHID + h] = a0 + bv;
            out[(long)(b0 + 1) * NHID + h] = a1 + bv;
        }
    }
}

extern "C" void kernel_launch(void* const* d_in, const int* in_sizes, int n_in,
                              void* d_out, int out_size, void* d_ws, size_t ws_size,
                              hipStream_t stream)
{
    const float* vals  = (const float*)d_in[0];
    const float* time_ = (const float*)d_in[1];
    const int*   masks = (const int*)d_in[2];
    // d_in[3] = lengths (unused by the reference outputs)
    const float* l_t   = (const float*)d_in[4];
    const float* W     = (const float*)d_in[5];
    const float* bias  = (const float*)d_in[6];

    float* out  = (float*)d_out;                       // [B*NHID] grep, then [B] mid
    float* g_ws = (float*)d_ws;                        // 1 MB: g [B, GDIM]
    ull*   gm   = (ull*)((char*)d_ws + (1 << 20));     // 2 MB: bitmask words

    mask_kernel <<<2048, 256, 0, stream>>>(masks, gm);
    query_kernel<<<1024, 256, 0, stream>>>(vals, time_, gm, l_t,
                                           g_ws, out + (long)B_ * NHID);
    grep_kernel <<<1024, 256, 0, stream>>>(g_ws, l_t, W, bias, out);
}